// Round 3
// baseline (972.367 us; speedup 1.0000x reference)
//
#include <hip/hip_runtime.h>
#include <hip/hip_bf16.h>
#include <cmath>

// DXVAE: 7-node sequential graph GRU + VAE head, B=2048, H=1024. f32 I/O.
// R3: all GEMMs upgraded to the m97-verified structure: 128x128 tile,
// global_load_lds width=16 staging, 16 MFMA : 8 ds_read_b128 per K-step.
// GRU = augmented GEMM (gi folded as one extra K-step via [h|x] / [Whh|Wih])
// + small elementwise kernel. G buffer aliases P planes 0..3 (disjoint lifetime).

typedef __hip_bfloat16 bf16;
typedef __attribute__((ext_vector_type(8))) short bf16x8;   // 8 bf16 (4 VGPRs)
typedef __attribute__((ext_vector_type(4))) float f32x4;    // C/D frag

constexpr int BATCH = 2048;
constexpr int HD    = 1024;
constexpr int LDA   = 1056;          // augmented A stride (1024 h + 32 x-pad)
constexpr size_t BH = (size_t)BATCH * HD;

__device__ __forceinline__ bf16  f2bf(float v){ return __float2bfloat16(v); }
__device__ __forceinline__ float sigm(float x){ return 1.0f/(1.0f+__expf(-x)); }

__device__ __forceinline__ void async16(bf16* lds, const bf16* g){
  __builtin_amdgcn_global_load_lds((const __attribute__((address_space(1))) void*)g,
                                   (__attribute__((address_space(3))) void*)lds, 16, 0, 0);
}
// 4 bf16 -> 4 f32 (exact: bits<<16)
__device__ __forceinline__ void ld4f(const bf16* p, float* o){
  ushort4 u = *reinterpret_cast<const ushort4*>(p);
  o[0] = __uint_as_float(((unsigned)u.x)<<16);
  o[1] = __uint_as_float(((unsigned)u.y)<<16);
  o[2] = __uint_as_float(((unsigned)u.z)<<16);
  o[3] = __uint_as_float(((unsigned)u.w)<<16);
}
__device__ __forceinline__ void st4bf(bf16* p, const float* v){
  bf16 o[4] = {f2bf(v[0]), f2bf(v[1]), f2bf(v[2]), f2bf(v[3])};
  *reinterpret_cast<ushort4*>(p) = *reinterpret_cast<const ushort4*>(o);
}

// ---------------------------------------------------------------------------
// Weight packing (once per launch)
// ---------------------------------------------------------------------------
// W_aug (4096 x 1056): rows 0..1023 [Whh_r|Wih_r], 1024..2047 [Whh_z|Wih_z],
// 2048..3071 [Whh_n|0], 3072..4095 [0|Wih_n] (first 1024 cols never read).
__global__ __launch_bounds__(256) void pack_waug(
    const float* __restrict__ Whh, const float* __restrict__ Wih, int xw,
    bf16* __restrict__ out)
{
  int c = blockIdx.x;                 // 0..4095
  int g = c >> 10, h = c & 1023;
  for (int ch = threadIdx.x; ch < 264; ch += 256){
    int f0 = ch*4;
    float v[4] = {0.f,0.f,0.f,0.f};
    if (f0 < 1024){
      if (g < 3){
        const float4 t = *reinterpret_cast<const float4*>(Whh + (size_t)(g==2 ? 2048+h : g*1024+h)*1024 + f0);
        v[0]=t.x; v[1]=t.y; v[2]=t.z; v[3]=t.w;
      }
    } else if (g != 2){
      int src = (g==0) ? h : (g==1) ? 1024+h : 2048+h;
      int fx = f0 - 1024;
      #pragma unroll
      for (int j=0;j<4;++j) if (fx+j < xw) v[j] = Wih[(size_t)src*xw + fx + j];
    }
    st4bf(out + (size_t)c*LDA + f0, v);
  }
}

// Wgm (4096x1024) = [Wg[:,:1024]; Wg[:,1024:]; Wm[:,:1024]; Wm[:,1024:]]
__global__ __launch_bounds__(256) void pack_wgm(const float* __restrict__ Wg,
    const float* __restrict__ Wm, bf16* __restrict__ outW){
  int i = blockIdx.x*256 + threadIdx.x;          // < 4096*256
  int c = i >> 8, f0 = (i & 255)*4;
  int j = c >> 10, h = c & 1023;
  const float* src = (j < 2) ? Wg : Wm;
  float4 t = *reinterpret_cast<const float4*>(src + (size_t)h*2048 + ((j & 1) ? 1024 : 0) + f0);
  float v[4] = {t.x,t.y,t.z,t.w};
  st4bf(outW + (size_t)c*1024 + f0, v);
}

// Wms (512x1024) = [Wmu; Wstd]
__global__ __launch_bounds__(256) void pack_wms(const float* __restrict__ Wmu,
    const float* __restrict__ Wstd, bf16* __restrict__ outW){
  int i = blockIdx.x*256 + threadIdx.x;          // < 512*256
  int c = i >> 8, f0 = (i & 255)*4;
  const float* src = (c < 256) ? (Wmu + (size_t)c*1024) : (Wstd + (size_t)(c-256)*1024);
  float4 t = *reinterpret_cast<const float4*>(src + f0);
  float v[4] = {t.x,t.y,t.z,t.w};
  st4bf(outW + (size_t)c*1024 + f0, v);
}

// Xpad (7 x 2048 x 32): X[:,v,:27] zero-padded to 32, bf16
__global__ __launch_bounds__(256) void pack_xpad(const float* __restrict__ X,
    bf16* __restrict__ out){
  int i = blockIdx.x*256 + threadIdx.x;          // < 7*2048*32
  int f = i & 31, bv = i >> 5;
  int b = bv / 7, v = bv % 7;
  float val = (f < 27) ? X[((size_t)b*7 + v)*27 + f] : 0.f;
  out[((size_t)v*BATCH + b)*32 + f] = f2bf(val);
}
// XpadR (2048 x 32): X[:,0,:23] zero-padded, bf16
__global__ __launch_bounds__(256) void pack_xpr(const float* __restrict__ X,
    bf16* __restrict__ out){
  int i = blockIdx.x*256 + threadIdx.x;          // < 2048*32
  int f = i & 31, b = i >> 5;
  float val = (f < 23) ? X[(size_t)b*7*27 + f] : 0.f;
  out[(size_t)b*32 + f] = f2bf(val);
}

// ---------------------------------------------------------------------------
// Stage combine: Hin[b, 0:1024] = sum_{k>v} sigm(p*Pg1+s*Pg2+bg)*(p*Pm1+s*Pm2)
// Hin[b, 1024:1056] = x-tail (from tailsrc). v==6: empty loop -> zeros + tail.
// ---------------------------------------------------------------------------
__global__ __launch_bounds__(256) void combine_k(
    const bf16* __restrict__ P, const int* __restrict__ adj,
    const float* __restrict__ bg, const bf16* __restrict__ tailsrc,
    bf16* __restrict__ Hin, int v)
{
  int t  = threadIdx.x;
  int b  = blockIdx.x*2 + (t>>7);
  int tl = t & 127;
  int h0 = tl*8;
  float acc[8] = {0,0,0,0,0,0,0,0};
  float bgv[8]; ld4f_dummy: ;
  { const float4 a = *reinterpret_cast<const float4*>(bg + h0);
    const float4 c = *reinterpret_cast<const float4*>(bg + h0 + 4);
    bgv[0]=a.x;bgv[1]=a.y;bgv[2]=a.z;bgv[3]=a.w;bgv[4]=c.x;bgv[5]=c.y;bgv[6]=c.z;bgv[7]=c.w; }
  for (int k=v+1;k<7;++k){
    bool p = adj[b*49 + k*7 + v] > 0;
    bool s = adj[b*49 + v*7 + k] > 0;
    if (!p && !s) continue;
    const bf16* base = P + (size_t)(k-1)*4*BH + (size_t)b*HD + h0;
    float g1[8], g2[8], m1[8], m2[8];
    ld4f(base,          g1); ld4f(base+4,        g1+4);
    ld4f(base+BH,       g2); ld4f(base+BH+4,     g2+4);
    ld4f(base+2*BH,     m1); ld4f(base+2*BH+4,   m1+4);
    ld4f(base+3*BH,     m2); ld4f(base+3*BH+4,   m2+4);
    #pragma unroll
    for (int u=0;u<8;++u){
      float gg = (p?g1[u]:0.f) + (s?g2[u]:0.f);
      float mm = (p?m1[u]:0.f) + (s?m2[u]:0.f);
      acc[u] += sigm(gg + bgv[u]) * mm;
    }
  }
  st4bf(Hin + (size_t)b*LDA + h0,     acc);
  st4bf(Hin + (size_t)b*LDA + h0 + 4, acc+4);
  if (tl < 4){   // x-tail: 32 elems per row, 4 threads x 8
    const ushort4* s0 = reinterpret_cast<const ushort4*>(tailsrc + (size_t)b*32 + tl*8);
    ushort4* d0 = reinterpret_cast<ushort4*>(Hin + (size_t)b*LDA + 1024 + tl*8);
    d0[0] = s0[0]; d0[1] = s0[1];
  }
}

// ---------------------------------------------------------------------------
// GRU elementwise: reads G strips {pre_r, pre_z, hn, inn}, h; writes h' and
// (tail_mode) the self-loop-masked x tail for the next GEMM.
// ---------------------------------------------------------------------------
__global__ __launch_bounds__(256) void gru_ew(
    const bf16* __restrict__ G, const bf16* __restrict__ h,
    const float* __restrict__ bih, const float* __restrict__ bhh,
    bf16* __restrict__ out, const int* __restrict__ adj,
    const bf16* __restrict__ xpad, int v, int tail_mode)
{
  int b = blockIdx.x, t = threadIdx.x, c = t*4;
  float g0[4], g1[4], g2[4], g3[4], hv[4];
  const bf16* Gb = G + (size_t)b*4096 + c;
  ld4f(Gb,        g0); ld4f(Gb+1024, g1); ld4f(Gb+2048, g2); ld4f(Gb+3072, g3);
  ld4f(h + (size_t)b*LDA + c, hv);
  float4 bi0 = *reinterpret_cast<const float4*>(bih + c);
  float4 bi1 = *reinterpret_cast<const float4*>(bih + 1024 + c);
  float4 bi2 = *reinterpret_cast<const float4*>(bih + 2048 + c);
  float4 bh0 = *reinterpret_cast<const float4*>(bhh + c);
  float4 bh1 = *reinterpret_cast<const float4*>(bhh + 1024 + c);
  float4 bh2 = *reinterpret_cast<const float4*>(bhh + 2048 + c);
  const float* pbi0=&bi0.x; const float* pbi1=&bi1.x; const float* pbi2=&bi2.x;
  const float* pbh0=&bh0.x; const float* pbh1=&bh1.x; const float* pbh2=&bh2.x;
  float o[4];
  #pragma unroll
  for (int i=0;i<4;++i){
    float r = sigm(g0[i] + pbi0[i] + pbh0[i]);
    float z = sigm(g1[i] + pbi1[i] + pbh1[i]);
    float n = tanhf(g3[i] + pbi2[i] + r*(g2[i] + pbh2[i]));
    o[i] = (1.f - z)*n + z*hv[i];
  }
  st4bf(out + (size_t)b*LDA + c, o);
  if (tail_mode && t < 8){
    bool self = adj[b*49 + v*8] > 0;
    ushort4 tv = {0,0,0,0};
    if (self) tv = *reinterpret_cast<const ushort4*>(xpad + (size_t)b*32 + t*4);
    *reinterpret_cast<ushort4*>(out + (size_t)b*LDA + 1024 + t*4) = tv;
  }
}

// ---------------------------------------------------------------------------
// m97-style GEMM: C = A(2048 x K) @ B^T(N x K), 128x128 tile, BK=32,
// global_load_lds(16B) staging. 4 waves 2x2; wave = 64x64 = 4x4 MFMA tiles.
// MODE 0: GRU G-output (N=4096, strip-dependent K range, row-major ld 4096)
// MODE 1: P-plane output (N=4096)
// MODE 2: mu/std head (N=512, f32 out, bias+softplus)
// ---------------------------------------------------------------------------
template<int MODE>
__global__ __launch_bounds__(256) void gemm128(
    const bf16* __restrict__ A, const bf16* __restrict__ Bm,
    bf16* __restrict__ out, float* __restrict__ outF,
    int lda, int ldb, int kmain, int ktot, int hz,
    const float* __restrict__ bmu, const float* __restrict__ bstd)
{
  __shared__ __align__(16) bf16 As[128*32];
  __shared__ __align__(16) bf16 Bs[128*32];
  const int tid  = threadIdx.x;
  const int rb0  = blockIdx.x*128, n0 = blockIdx.y*128;
  const int lane = tid & 63, wid = tid >> 6;
  const int wm   = wid >> 1, wn = wid & 1;          // wave 2x2 -> 64x64
  const int quad = lane >> 4, l15 = lane & 15;
  const int lr   = lane >> 2, lc = (lane & 3)*8;    // staging lane -> row/col

  int kb = 0, ke = ktot;
  if (MODE == 0){
    int g = n0 >> 10;                               // gate strip
    if (hz){ kb = kmain; if (g==2) ke = kmain; }    // h==0: only x-tail K-step
    else   { if (g==3) kb = kmain; if (g==2) ke = kmain; }
  }

  const bf16* ga = A  + (size_t)(rb0 + wid*32 + lr)*lda + lc;
  const bf16* gb = Bm + (size_t)(n0  + wid*32 + lr)*ldb + lc;
  bf16* lA = As + wid*32*32;                        // wave-uniform LDS base
  bf16* lB = Bs + wid*32*32;

  f32x4 acc[4][4] = {};
  for (int k0 = kb; k0 < ke; k0 += 32){
    async16(lA,       ga + k0);
    async16(lA + 512, ga + k0 + (size_t)16*lda);
    async16(lB,       gb + k0);
    async16(lB + 512, gb + k0 + (size_t)16*ldb);
    __syncthreads();                                // drains vmcnt, barrier
    bf16x8 af[4], bfr[4];
    #pragma unroll
    for (int t=0;t<4;++t){
      af[t]  = *reinterpret_cast<const bf16x8*>(&As[(wm*64 + t*16 + l15)*32 + quad*8]);
      bfr[t] = *reinterpret_cast<const bf16x8*>(&Bs[(wn*64 + t*16 + l15)*32 + quad*8]);
    }
    #pragma unroll
    for (int tm=0;tm<4;++tm)
      #pragma unroll
      for (int tn=0;tn<4;++tn)
        acc[tm][tn] = __builtin_amdgcn_mfma_f32_16x16x32_bf16(af[tm], bfr[tn], acc[tm][tn], 0,0,0);
    __syncthreads();                                // LDS reuse guard
  }

  // Epilogue. C/D layout: col=lane&15, row=quad*4+i.
  #pragma unroll
  for (int tm=0;tm<4;++tm)
    #pragma unroll
    for (int tn=0;tn<4;++tn)
      #pragma unroll
      for (int i=0;i<4;++i){
        int b = rb0 + wm*64 + tm*16 + quad*4 + i;
        int c = n0  + wn*64 + tn*16 + l15;
        float val = acc[tm][tn][i];
        if (MODE == 0){
          out[(size_t)b*4096 + c] = f2bf(val);
        } else if (MODE == 1){
          out[((size_t)(c>>10)*BATCH + b)*HD + (c & 1023)] = f2bf(val);
        } else {
          if (c < 256){
            outF[(size_t)b*256 + c] = val + bmu[c];
          } else {
            val += bstd[c-256];
            val = fmaxf(val,0.f) + log1pf(__expf(-fabsf(val)));   // stable softplus
            outF[(size_t)BATCH*256 + (size_t)b*256 + (c-256)] = val;
          }
        }
      }
}

// ---------------------------------------------------------------------------
extern "C" void kernel_launch(void* const* d_in, const int* in_sizes, int n_in,
                              void* d_out, int out_size, void* d_ws, size_t ws_size,
                              hipStream_t stream)
{
  const float* X    = (const float*)d_in[0];
  const int*   adj  = (const int*)  d_in[1];
  const float* Wihc = (const float*)d_in[2];
  const float* Whhc = (const float*)d_in[3];
  const float* bihc = (const float*)d_in[4];
  const float* bhhc = (const float*)d_in[5];
  const float* Wihl = (const float*)d_in[6];
  const float* Whhl = (const float*)d_in[7];
  const float* bihl = (const float*)d_in[8];
  const float* bhhl = (const float*)d_in[9];
  const float* Wihr = (const float*)d_in[10];
  const float* Whhr = (const float*)d_in[11];
  const float* bihr = (const float*)d_in[12];
  const float* bhhr = (const float*)d_in[13];
  const float* Wg   = (const float*)d_in[14];
  const float* bg   = (const float*)d_in[15];
  const float* Wm   = (const float*)d_in[16];
  const float* Wmu  = (const float*)d_in[17];
  const float* bmu  = (const float*)d_in[18];
  const float* Wstd = (const float*)d_in[19];
  const float* bstd = (const float*)d_in[20];
  float* out = (float*)d_out;

  // Workspace (bf16 elems, all 16B-aligned). G aliases P planes 0..3:
  // planes 0..3 are written only by stage v=1's P-GEMM (after G's last read
  // there) and read only by v=0's combine (before G's next write).
  bf16* P    = (bf16*)d_ws;                      // 24*BH
  bf16* G    = P;                                // alias, 2048*4096 == 4*BH
  bf16* Hin  = P    + 24*BH;                     // 2048*1056
  bf16* Hva  = Hin  + (size_t)BATCH*LDA;
  bf16* Hvb  = Hva  + (size_t)BATCH*LDA;
  bf16* Wca  = Hvb  + (size_t)BATCH*LDA;         // 4096*1056
  bf16* Wla  = Wca  + (size_t)4096*LDA;
  bf16* Wra  = Wla  + (size_t)4096*LDA;
  bf16* Wgm  = Wra  + (size_t)4096*LDA;          // 4096*1024
  bf16* Wms  = Wgm  + (size_t)4096*1024;         // 512*1024
  bf16* Xp   = Wms  + (size_t)512*1024;          // 7*2048*32
  bf16* XpR  = Xp   + (size_t)7*BATCH*32;        // 2048*32

  pack_waug<<<4096, 256, 0, stream>>>(Whhc, Wihc, 27, Wca);
  pack_waug<<<4096, 256, 0, stream>>>(Whhl, Wihl, 27, Wla);
  pack_waug<<<4096, 256, 0, stream>>>(Whhr, Wihr, 23, Wra);
  pack_wgm <<<4096, 256, 0, stream>>>(Wg, Wm, Wgm);
  pack_wms <<<512,  256, 0, stream>>>(Wmu, Wstd, Wms);
  pack_xpad<<<1792, 256, 0, stream>>>(X, Xp);
  pack_xpr <<<256,  256, 0, stream>>>(X, XpR);

  for (int v=6; v>=1; --v){
    const bf16* xt = Xp + (size_t)v*BATCH*32;
    combine_k<<<1024, 256, 0, stream>>>(P, adj, bg, xt, Hin, v);
    // GRU-c
    gemm128<0><<<dim3(16,32), 256, 0, stream>>>(Hin, Wca, G, nullptr,
        LDA, LDA, 1024, 1056, (v==6)?1:0, nullptr, nullptr);
    gru_ew<<<2048, 256, 0, stream>>>(G, Hin, bihc, bhhc, Hva, adj, xt, v, 1);
    // GRU-l (x tail in Hva was self-loop-masked by gru_ew)
    gemm128<0><<<dim3(16,32), 256, 0, stream>>>(Hva, Wla, G, nullptr,
        LDA, LDA, 1024, 1056, 0, nullptr, nullptr);
    gru_ew<<<2048, 256, 0, stream>>>(G, Hva, bihl, bhhl, Hvb, adj, nullptr, v, 0);
    // P projections for node v
    gemm128<1><<<dim3(16,32), 256, 0, stream>>>(Hvb, Wgm, P + (size_t)(v-1)*4*BH,
        nullptr, LDA, 1024, 1024, 1024, 0, nullptr, nullptr);
  }
  combine_k<<<1024, 256, 0, stream>>>(P, adj, bg, XpR, Hin, 0);
  gemm128<0><<<dim3(16,32), 256, 0, stream>>>(Hin, Wra, G, nullptr,
      LDA, LDA, 1024, 1056, 0, nullptr, nullptr);
  gru_ew<<<2048, 256, 0, stream>>>(G, Hin, bihr, bhhr, Hva, adj, nullptr, 0, 0);
  gemm128<2><<<dim3(16,4), 256, 0, stream>>>(Hva, Wms, nullptr, out,
      LDA, 1024, 1024, 1024, 0, bmu, bstd);
}

// Round 4
// 919.625 us; speedup vs baseline: 1.0574x; 1.0574x over previous
//
#include <hip/hip_runtime.h>
#include <hip/hip_bf16.h>
#include <cmath>

// DXVAE: 7-node sequential graph GRU + VAE head, B=2048, H=1024. f32 I/O.
// R4: gemm128 K-loop rebuilt BARRIER-FREE: per-wave private LDS staging
// (each wave DMAs its own 64x32 A and B tiles, double-buffered, prefetch
// 1 step ahead, manual s_waitcnt vmcnt(8)). No __syncthreads in the K-loop:
// all DMA->ds_read deps are same-wave, so waves self-pipeline independently
// -- removes the vmcnt(0)+barrier drain that serialized R3 at 2 blocks/CU.
// GRU = augmented GEMM (gi folded as one extra K-step via [h|x] / [Whh|Wih])
// + small elementwise kernel. G buffer aliases P planes 0..3.

typedef __hip_bfloat16 bf16;
typedef __attribute__((ext_vector_type(8))) short bf16x8;   // 8 bf16 (4 VGPRs)
typedef __attribute__((ext_vector_type(4))) float f32x4;    // C/D frag

constexpr int BATCH = 2048;
constexpr int HD    = 1024;
constexpr int LDA   = 1056;          // augmented A stride (1024 h + 32 x-pad)
constexpr size_t BH = (size_t)BATCH * HD;

__device__ __forceinline__ bf16  f2bf(float v){ return __float2bfloat16(v); }
__device__ __forceinline__ float sigm(float x){ return 1.0f/(1.0f+__expf(-x)); }

__device__ __forceinline__ void async16(bf16* lds, const bf16* g){
  __builtin_amdgcn_global_load_lds((const __attribute__((address_space(1))) void*)g,
                                   (__attribute__((address_space(3))) void*)lds, 16, 0, 0);
}
// 4 bf16 -> 4 f32 (exact: bits<<16)
__device__ __forceinline__ void ld4f(const bf16* p, float* o){
  ushort4 u = *reinterpret_cast<const ushort4*>(p);
  o[0] = __uint_as_float(((unsigned)u.x)<<16);
  o[1] = __uint_as_float(((unsigned)u.y)<<16);
  o[2] = __uint_as_float(((unsigned)u.z)<<16);
  o[3] = __uint_as_float(((unsigned)u.w)<<16);
}
__device__ __forceinline__ void st4bf(bf16* p, const float* v){
  bf16 o[4] = {f2bf(v[0]), f2bf(v[1]), f2bf(v[2]), f2bf(v[3])};
  *reinterpret_cast<ushort4*>(p) = *reinterpret_cast<const ushort4*>(o);
}

// ---------------------------------------------------------------------------
// Weight packing (once per launch)
// ---------------------------------------------------------------------------
// W_aug (4096 x 1056): rows 0..1023 [Whh_r|Wih_r], 1024..2047 [Whh_z|Wih_z],
// 2048..3071 [Whh_n|0], 3072..4095 [0|Wih_n] (first 1024 cols never read).
__global__ __launch_bounds__(256) void pack_waug(
    const float* __restrict__ Whh, const float* __restrict__ Wih, int xw,
    bf16* __restrict__ out)
{
  int c = blockIdx.x;                 // 0..4095
  int g = c >> 10, h = c & 1023;
  for (int ch = threadIdx.x; ch < 264; ch += 256){
    int f0 = ch*4;
    float v[4] = {0.f,0.f,0.f,0.f};
    if (f0 < 1024){
      if (g < 3){
        const float4 t = *reinterpret_cast<const float4*>(Whh + (size_t)(g==2 ? 2048+h : g*1024+h)*1024 + f0);
        v[0]=t.x; v[1]=t.y; v[2]=t.z; v[3]=t.w;
      }
    } else if (g != 2){
      int src = (g==0) ? h : (g==1) ? 1024+h : 2048+h;
      int fx = f0 - 1024;
      #pragma unroll
      for (int j=0;j<4;++j) if (fx+j < xw) v[j] = Wih[(size_t)src*xw + fx + j];
    }
    st4bf(out + (size_t)c*LDA + f0, v);
  }
}

// Wgm (4096x1024) = [Wg[:,:1024]; Wg[:,1024:]; Wm[:,:1024]; Wm[:,1024:]]
__global__ __launch_bounds__(256) void pack_wgm(const float* __restrict__ Wg,
    const float* __restrict__ Wm, bf16* __restrict__ outW){
  int i = blockIdx.x*256 + threadIdx.x;          // < 4096*256
  int c = i >> 8, f0 = (i & 255)*4;
  int j = c >> 10, h = c & 1023;
  const float* src = (j < 2) ? Wg : Wm;
  float4 t = *reinterpret_cast<const float4*>(src + (size_t)h*2048 + ((j & 1) ? 1024 : 0) + f0);
  float v[4] = {t.x,t.y,t.z,t.w};
  st4bf(outW + (size_t)c*1024 + f0, v);
}

// Wms (512x1024) = [Wmu; Wstd]
__global__ __launch_bounds__(256) void pack_wms(const float* __restrict__ Wmu,
    const float* __restrict__ Wstd, bf16* __restrict__ outW){
  int i = blockIdx.x*256 + threadIdx.x;          // < 512*256
  int c = i >> 8, f0 = (i & 255)*4;
  const float* src = (c < 256) ? (Wmu + (size_t)c*1024) : (Wstd + (size_t)(c-256)*1024);
  float4 t = *reinterpret_cast<const float4*>(src + f0);
  float v[4] = {t.x,t.y,t.z,t.w};
  st4bf(outW + (size_t)c*1024 + f0, v);
}

// Xpad (7 x 2048 x 32): X[:,v,:27] zero-padded to 32, bf16
__global__ __launch_bounds__(256) void pack_xpad(const float* __restrict__ X,
    bf16* __restrict__ out){
  int i = blockIdx.x*256 + threadIdx.x;          // < 7*2048*32
  int f = i & 31, bv = i >> 5;
  int b = bv / 7, v = bv % 7;
  float val = (f < 27) ? X[((size_t)b*7 + v)*27 + f] : 0.f;
  out[((size_t)v*BATCH + b)*32 + f] = f2bf(val);
}
// XpadR (2048 x 32): X[:,0,:23] zero-padded, bf16
__global__ __launch_bounds__(256) void pack_xpr(const float* __restrict__ X,
    bf16* __restrict__ out){
  int i = blockIdx.x*256 + threadIdx.x;          // < 2048*32
  int f = i & 31, b = i >> 5;
  float val = (f < 23) ? X[(size_t)b*7*27 + f] : 0.f;
  out[(size_t)b*32 + f] = f2bf(val);
}

// ---------------------------------------------------------------------------
// Stage combine: Hin[b, 0:1024] = sum_{k>v} sigm(p*Pg1+s*Pg2+bg)*(p*Pm1+s*Pm2)
// Hin[b, 1024:1056] = x-tail (from tailsrc). v==6: empty loop -> zeros + tail.
// ---------------------------------------------------------------------------
__global__ __launch_bounds__(256) void combine_k(
    const bf16* __restrict__ P, const int* __restrict__ adj,
    const float* __restrict__ bg, const bf16* __restrict__ tailsrc,
    bf16* __restrict__ Hin, int v)
{
  int t  = threadIdx.x;
  int b  = blockIdx.x*2 + (t>>7);
  int tl = t & 127;
  int h0 = tl*8;
  float acc[8] = {0,0,0,0,0,0,0,0};
  float bgv[8];
  { const float4 a = *reinterpret_cast<const float4*>(bg + h0);
    const float4 c = *reinterpret_cast<const float4*>(bg + h0 + 4);
    bgv[0]=a.x;bgv[1]=a.y;bgv[2]=a.z;bgv[3]=a.w;bgv[4]=c.x;bgv[5]=c.y;bgv[6]=c.z;bgv[7]=c.w; }
  for (int k=v+1;k<7;++k){
    bool p = adj[b*49 + k*7 + v] > 0;
    bool s = adj[b*49 + v*7 + k] > 0;
    if (!p && !s) continue;
    const bf16* base = P + (size_t)(k-1)*4*BH + (size_t)b*HD + h0;
    float g1[8], g2[8], m1[8], m2[8];
    ld4f(base,          g1); ld4f(base+4,        g1+4);
    ld4f(base+BH,       g2); ld4f(base+BH+4,     g2+4);
    ld4f(base+2*BH,     m1); ld4f(base+2*BH+4,   m1+4);
    ld4f(base+3*BH,     m2); ld4f(base+3*BH+4,   m2+4);
    #pragma unroll
    for (int u=0;u<8;++u){
      float gg = (p?g1[u]:0.f) + (s?g2[u]:0.f);
      float mm = (p?m1[u]:0.f) + (s?m2[u]:0.f);
      acc[u] += sigm(gg + bgv[u]) * mm;
    }
  }
  st4bf(Hin + (size_t)b*LDA + h0,     acc);
  st4bf(Hin + (size_t)b*LDA + h0 + 4, acc+4);
  if (tl < 4){   // x-tail: 32 elems per row, 4 threads x 8
    const ushort4* s0 = reinterpret_cast<const ushort4*>(tailsrc + (size_t)b*32 + tl*8);
    ushort4* d0 = reinterpret_cast<ushort4*>(Hin + (size_t)b*LDA + 1024 + tl*8);
    d0[0] = s0[0]; d0[1] = s0[1];
  }
}

// ---------------------------------------------------------------------------
// GRU elementwise: reads G strips {pre_r, pre_z, hn, inn}, h; writes h' and
// (tail_mode) the self-loop-masked x tail for the next GEMM.
// ---------------------------------------------------------------------------
__global__ __launch_bounds__(256) void gru_ew(
    const bf16* __restrict__ G, const bf16* __restrict__ h,
    const float* __restrict__ bih, const float* __restrict__ bhh,
    bf16* __restrict__ out, const int* __restrict__ adj,
    const bf16* __restrict__ xpad, int v, int tail_mode)
{
  int b = blockIdx.x, t = threadIdx.x, c = t*4;
  float g0[4], g1[4], g2[4], g3[4], hv[4];
  const bf16* Gb = G + (size_t)b*4096 + c;
  ld4f(Gb,        g0); ld4f(Gb+1024, g1); ld4f(Gb+2048, g2); ld4f(Gb+3072, g3);
  ld4f(h + (size_t)b*LDA + c, hv);
  float4 bi0 = *reinterpret_cast<const float4*>(bih + c);
  float4 bi1 = *reinterpret_cast<const float4*>(bih + 1024 + c);
  float4 bi2 = *reinterpret_cast<const float4*>(bih + 2048 + c);
  float4 bh0 = *reinterpret_cast<const float4*>(bhh + c);
  float4 bh1 = *reinterpret_cast<const float4*>(bhh + 1024 + c);
  float4 bh2 = *reinterpret_cast<const float4*>(bhh + 2048 + c);
  const float* pbi0=&bi0.x; const float* pbi1=&bi1.x; const float* pbi2=&bi2.x;
  const float* pbh0=&bh0.x; const float* pbh1=&bh1.x; const float* pbh2=&bh2.x;
  float o[4];
  #pragma unroll
  for (int i=0;i<4;++i){
    float r = sigm(g0[i] + pbi0[i] + pbh0[i]);
    float z = sigm(g1[i] + pbi1[i] + pbh1[i]);
    float n = tanhf(g3[i] + pbi2[i] + r*(g2[i] + pbh2[i]));
    o[i] = (1.f - z)*n + z*hv[i];
  }
  st4bf(out + (size_t)b*LDA + c, o);
  if (tail_mode && t < 8){
    bool self = adj[b*49 + v*8] > 0;
    ushort4 tv = {0,0,0,0};
    if (self) tv = *reinterpret_cast<const ushort4*>(xpad + (size_t)b*32 + t*4);
    *reinterpret_cast<ushort4*>(out + (size_t)b*LDA + 1024 + t*4) = tv;
  }
}

// ---------------------------------------------------------------------------
// Barrier-free GEMM: C = A(2048 x K) @ B^T(N x K), 128x128 tile, BK=32.
// Each wave computes 64x64 and stages its OWN A(64x32)+B(64x32) tiles into
// private LDS (8 KB/buf, double-buffered) via global_load_lds; prefetch one
// step ahead; manual s_waitcnt vmcnt(8). NO __syncthreads in the K-loop --
// all DMA->ds_read dependencies are same-wave.
// MODE 0: GRU G-output (N=4096, strip-dependent K range, row-major ld 4096)
// MODE 1: P-plane output (N=4096)
// MODE 2: mu/std head (N=512, f32 out, bias+softplus)
// ---------------------------------------------------------------------------
template<int MODE>
__global__ __launch_bounds__(256) void gemm128(
    const bf16* __restrict__ A, const bf16* __restrict__ Bm,
    bf16* __restrict__ out, float* __restrict__ outF,
    int lda, int ldb, int kmain, int ktot, int hz,
    const float* __restrict__ bmu, const float* __restrict__ bstd)
{
  // 4 waves x 2 buffers x (A 2048 + B 2048 elems) = 64 KB
  __shared__ __align__(16) bf16 Sh[32768];
  const int tid  = threadIdx.x;
  const int rb0  = blockIdx.x*128, n0 = blockIdx.y*128;
  const int lane = tid & 63, wid = tid >> 6;
  const int wm   = wid >> 1, wn = wid & 1;          // wave 2x2 -> 64x64 tile
  const int quad = lane >> 4, l15 = lane & 15;
  const int lr   = lane >> 2, lc = (lane & 3)*8;    // DMA lane -> row/col

  int kb = 0, ke = ktot;
  if (MODE == 0){
    int g = n0 >> 10;                               // gate strip
    if (hz){ kb = kmain; if (g==2) ke = kmain; }    // h==0: only x-tail K-step
    else   { if (g==3) kb = kmain; if (g==2) ke = kmain; }
  }
  const int nk = (ke - kb) >> 5;

  const bf16* Ag = A  + (size_t)(rb0 + wm*64 + lr)*lda + lc + kb;
  const bf16* Bg = Bm + (size_t)(n0  + wn*64 + lr)*ldb + lc + kb;
  bf16* Wb = Sh + wid*8192;                         // wave-private LDS

  f32x4 acc[4][4] = {};
  if (nk > 0){
    #pragma unroll
    for (int i=0;i<4;++i) async16(Wb + i*512,        Ag + (size_t)(i*16)*lda);
    #pragma unroll
    for (int i=0;i<4;++i) async16(Wb + 2048 + i*512, Bg + (size_t)(i*16)*ldb);
  }
  for (int s=0; s<nk; ++s){
    const int j = s & 1;
    bf16* buf = Wb + j*4096;
    if (s+1 < nk){
      bf16* nb = Wb + (j^1)*4096;
      const bf16* nA = Ag + (size_t)(s+1)*32;
      const bf16* nB = Bg + (size_t)(s+1)*32;
      #pragma unroll
      for (int i=0;i<4;++i) async16(nb + i*512,        nA + (size_t)(i*16)*lda);
      #pragma unroll
      for (int i=0;i<4;++i) async16(nb + 2048 + i*512, nB + (size_t)(i*16)*ldb);
      __builtin_amdgcn_s_waitcnt(0xF78);   // vmcnt<=8: this step's 8 loads done
    } else {
      __builtin_amdgcn_s_waitcnt(0xF70);   // vmcnt(0): last step, drain all
    }
    bf16x8 af[4], bfr[4];
    #pragma unroll
    for (int t=0;t<4;++t){
      af[t]  = *reinterpret_cast<const bf16x8*>(&buf[(t*16 + l15)*32 + quad*8]);
      bfr[t] = *reinterpret_cast<const bf16x8*>(&buf[2048 + (t*16 + l15)*32 + quad*8]);
    }
    #pragma unroll
    for (int tm=0;tm<4;++tm)
      #pragma unroll
      for (int tn=0;tn<4;++tn)
        acc[tm][tn] = __builtin_amdgcn_mfma_f32_16x16x32_bf16(af[tm], bfr[tn], acc[tm][tn], 0,0,0);
  }

  // Epilogue. C/D layout: col=lane&15, row=quad*4+i.
  #pragma unroll
  for (int tm=0;tm<4;++tm)
    #pragma unroll
    for (int tn=0;tn<4;++tn)
      #pragma unroll
      for (int i=0;i<4;++i){
        int b = rb0 + wm*64 + tm*16 + quad*4 + i;
        int c = n0  + wn*64 + tn*16 + l15;
        float val = acc[tm][tn][i];
        if (MODE == 0){
          out[(size_t)b*4096 + c] = f2bf(val);
        } else if (MODE == 1){
          out[((size_t)(c>>10)*BATCH + b)*HD + (c & 1023)] = f2bf(val);
        } else {
          if (c < 256){
            outF[(size_t)b*256 + c] = val + bmu[c];
          } else {
            val += bstd[c-256];
            val = fmaxf(val,0.f) + log1pf(__expf(-fabsf(val)));   // stable softplus
            outF[(size_t)BATCH*256 + (size_t)b*256 + (c-256)] = val;
          }
        }
      }
}

// ---------------------------------------------------------------------------
extern "C" void kernel_launch(void* const* d_in, const int* in_sizes, int n_in,
                              void* d_out, int out_size, void* d_ws, size_t ws_size,
                              hipStream_t stream)
{
  const float* X    = (const float*)d_in[0];
  const int*   adj  = (const int*)  d_in[1];
  const float* Wihc = (const float*)d_in[2];
  const float* Whhc = (const float*)d_in[3];
  const float* bihc = (const float*)d_in[4];
  const float* bhhc = (const float*)d_in[5];
  const float* Wihl = (const float*)d_in[6];
  const float* Whhl = (const float*)d_in[7];
  const float* bihl = (const float*)d_in[8];
  const float* bhhl = (const float*)d_in[9];
  const float* Wihr = (const float*)d_in[10];
  const float* Whhr = (const float*)d_in[11];
  const float* bihr = (const float*)d_in[12];
  const float* bhhr = (const float*)d_in[13];
  const float* Wg   = (const float*)d_in[14];
  const float* bg   = (const float*)d_in[15];
  const float* Wm   = (const float*)d_in[16];
  const float* Wmu  = (const float*)d_in[17];
  const float* bmu  = (const float*)d_in[18];
  const float* Wstd = (const float*)d_in[19];
  const float* bstd = (const float*)d_in[20];
  float* out = (float*)d_out;

  // Workspace (bf16 elems, all 16B-aligned). G aliases P planes 0..3:
  // planes 0..3 are written only by stage v=1's P-GEMM (after G's last read
  // there) and read only by v=0's combine (before G's next write).
  bf16* P    = (bf16*)d_ws;                      // 24*BH
  bf16* G    = P;                                // alias, 2048*4096 == 4*BH
  bf16* Hin  = P    + 24*BH;                     // 2048*1056
  bf16* Hva  = Hin  + (size_t)BATCH*LDA;
  bf16* Hvb  = Hva  + (size_t)BATCH*LDA;
  bf16* Wca  = Hvb  + (size_t)BATCH*LDA;         // 4096*1056
  bf16* Wla  = Wca  + (size_t)4096*LDA;
  bf16* Wra  = Wla  + (size_t)4096*LDA;
  bf16* Wgm  = Wra  + (size_t)4096*LDA;          // 4096*1024
  bf16* Wms  = Wgm  + (size_t)4096*1024;         // 512*1024
  bf16* Xp   = Wms  + (size_t)512*1024;          // 7*2048*32
  bf16* XpR  = Xp   + (size_t)7*BATCH*32;        // 2048*32

  pack_waug<<<4096, 256, 0, stream>>>(Whhc, Wihc, 27, Wca);
  pack_waug<<<4096, 256, 0, stream>>>(Whhl, Wihl, 27, Wla);
  pack_waug<<<4096, 256, 0, stream>>>(Whhr, Wihr, 23, Wra);
  pack_wgm <<<4096, 256, 0, stream>>>(Wg, Wm, Wgm);
  pack_wms <<<512,  256, 0, stream>>>(Wmu, Wstd, Wms);
  pack_xpad<<<1792, 256, 0, stream>>>(X, Xp);
  pack_xpr <<<256,  256, 0, stream>>>(X, XpR);

  for (int v=6; v>=1; --v){
    const bf16* xt = Xp + (size_t)v*BATCH*32;
    combine_k<<<1024, 256, 0, stream>>>(P, adj, bg, xt, Hin, v);
    // GRU-c
    gemm128<0><<<dim3(16,32), 256, 0, stream>>>(Hin, Wca, G, nullptr,
        LDA, LDA, 1024, 1056, (v==6)?1:0, nullptr, nullptr);
    gru_ew<<<2048, 256, 0, stream>>>(G, Hin, bihc, bhhc, Hva, adj, xt, v, 1);
    // GRU-l (x tail in Hva was self-loop-masked by gru_ew)
    gemm128<0><<<dim3(16,32), 256, 0, stream>>>(Hva, Wla, G, nullptr,
        LDA, LDA, 1024, 1056, 0, nullptr, nullptr);
    gru_ew<<<2048, 256, 0, stream>>>(G, Hva, bihl, bhhl, Hvb, adj, nullptr, v, 0);
    // P projections for node v
    gemm128<1><<<dim3(16,32), 256, 0, stream>>>(Hvb, Wgm, P + (size_t)(v-1)*4*BH,
        nullptr, LDA, 1024, 1024, 1024, 0, nullptr, nullptr);
  }
  combine_k<<<1024, 256, 0, stream>>>(P, adj, bg, XpR, Hin, 0);
  gemm128<0><<<dim3(16,32), 256, 0, stream>>>(Hin, Wra, G, nullptr,
      LDA, LDA, 1024, 1056, 0, nullptr, nullptr);
  gru_ew<<<2048, 256, 0, stream>>>(G, Hin, bihr, bhhr, Hva, adj, nullptr, 0, 0);
  gemm128<2><<<dim3(16,4), 256, 0, stream>>>(Hva, Wms, nullptr, out,
      LDA, 1024, 1024, 1024, 0, bmu, bstd);
}